// Round 1
// baseline (865.576 us; speedup 1.0000x reference)
//
#include <hip/hip_runtime.h>
#include <math.h>

#define N_RADIAL 8
#define N_PSEUDO 4
#define EMB_DIM 32
#define CUTOFF 5.0f
#define WIDTH 0.5f
#define SQRT3_4PI 0.48860251190291992f   /* sqrt(3/(4*pi)) */
#define INV_SQRT2 0.70710678118654752f
#define PI_F 3.14159265358979323846f

// ---------------------------------------------------------------------------
// G[tc][tn][n][k] = sum_q W_species[tn,q] * Emb[tc, n*4+q] * Wc[n*4+q, k]
// 4*4*8*3 = 384 floats. Folds Emb (center-species) + Wc + pseudo (neighbor-
// species) into one tiny table so each edge only contributes rank-1 Y[m]*s[k]
// (9 atomics) instead of the reference's 96-wide scatter.
// ---------------------------------------------------------------------------
__global__ void build_G_kernel(const float* __restrict__ W_species, // (4,4)
                               const float* __restrict__ Emb,       // (4,32)
                               const float* __restrict__ Wc,        // (32,3)
                               float* __restrict__ G) {
    int i = threadIdx.x;
    if (i >= 4 * 4 * 8 * 3) return;
    int k  = i % 3;
    int n  = (i / 3) % 8;
    int tn = (i / 24) % 4;
    int tc = i / 96;
    float acc = 0.0f;
    #pragma unroll
    for (int q = 0; q < N_PSEUDO; ++q) {
        int d = n * N_PSEUDO + q;
        acc += W_species[tn * N_PSEUDO + q] * Emb[tc * EMB_DIM + d] * Wc[d * 3 + k];
    }
    G[i] = acc;
}

// ---------------------------------------------------------------------------
// Edge kernel: one thread per edge. Computes the 3x3 rank-1 contribution
// Y[m] * s[k] and atomically accumulates into vacc[center][m][k].
// ---------------------------------------------------------------------------
__global__ void edge_kernel(const float* __restrict__ vecs,      // (E,3)
                            const int*   __restrict__ centers,   // (E,)
                            const int*   __restrict__ neighbors, // (E,)
                            const int*   __restrict__ species,   // (A,)
                            const float* __restrict__ G,         // (4,4,8,3)
                            float*       __restrict__ vacc,      // (A,3,3)
                            int E) {
    __shared__ float Gs[384];
    for (int i = threadIdx.x; i < 384; i += blockDim.x) Gs[i] = G[i];
    __syncthreads();

    int e = blockIdx.x * blockDim.x + threadIdx.x;
    if (e >= E) return;

    float vx = vecs[3 * e + 0];
    float vy = vecs[3 * e + 1];
    float vz = vecs[3 * e + 2];

    float r2 = vx * vx + vy * vy + vz * vz;
    float r  = sqrtf(r2);
    if (r >= CUTOFF) return;            // fcut == 0 exactly (jnp.where(r<CUTOFF,...))

    int c  = centers[e];
    int nb = neighbors[e];
    int tc = species[c];
    int tn = species[nb];

    float rinv = 1.0f / (r + 1e-10f);

    // ShiftedCosine cutoff
    float t = (r - (CUTOFF - WIDTH)) / WIDTH;
    t = fminf(fmaxf(t, 0.0f), 1.0f);
    float fcut = 0.5f * (1.0f + cosf(PI_F * t));

    // Radial: R[n] = sin((pi/CUTOFF) * r * (n+1)) / (r + 1e-10), n = 0..7
    // via Chebyshev recurrence sin((n+1)t) = 2cos(t) sin(nt) - sin((n-1)t).
    float theta = (PI_F / CUTOFF) * r;
    float s1, c1;
    sincosf(theta, &s1, &c1);
    float twoc  = 2.0f * c1;
    float sn_m1 = 0.0f;   // sin(0*theta)
    float sn    = s1;     // sin(1*theta)

    const float* Gp = &Gs[(tc * 4 + tn) * 24];  // G[tc][tn][*][*]
    float s0 = 0.0f, s1a = 0.0f, s2 = 0.0f;
    #pragma unroll
    for (int n = 0; n < N_RADIAL; ++n) {
        s0  = fmaf(sn, Gp[n * 3 + 0], s0);
        s1a = fmaf(sn, Gp[n * 3 + 1], s1a);
        s2  = fmaf(sn, Gp[n * 3 + 2], s2);
        float nxt = twoc * sn - sn_m1;
        sn_m1 = sn;
        sn = nxt;
    }
    float coef = rinv * fcut;
    s0 *= coef; s1a *= coef; s2 *= coef;

    // Y (m = -1,0,1) = (y, z, x)/r * sqrt(3/4pi)
    float Y0 = SQRT3_4PI * vy * rinv;
    float Y1 = SQRT3_4PI * vz * rinv;
    float Y2 = SQRT3_4PI * vx * rinv;

    float* base = vacc + (size_t)c * 9;
    atomicAdd(base + 0, Y0 * s0);
    atomicAdd(base + 1, Y0 * s1a);
    atomicAdd(base + 2, Y0 * s2);
    atomicAdd(base + 3, Y1 * s0);
    atomicAdd(base + 4, Y1 * s1a);
    atomicAdd(base + 5, Y1 * s2);
    atomicAdd(base + 6, Y2 * s0);
    atomicAdd(base + 7, Y2 * s1a);
    atomicAdd(base + 8, Y2 * s2);
}

// ---------------------------------------------------------------------------
// Finalize: v has columns k=0,1 summed; column k=2 = cross(v[:,0], v[:,1])/sqrt2.
// (CG tensor for l1=l2=1->L=1 in this basis is Levi-Civita/sqrt(2); the cyclic
// (y,z,x) relabeling leaves Levi-Civita invariant.)
// out[a][m][k]: k=0 -> v[m][0], k=1 -> v[m][1], k=2 -> v3[m].
// ---------------------------------------------------------------------------
__global__ void finalize_kernel(const float* __restrict__ vacc, // (A,3,3)
                                float* __restrict__ out,        // (A,3,3)
                                int A) {
    int a = blockIdx.x * blockDim.x + threadIdx.x;
    if (a >= A) return;

    const float* v = vacc + (size_t)a * 9;
    float a0 = v[0], b0 = v[1];   // m=0 : k=0,1
    float a1 = v[3], b1 = v[4];   // m=1
    float a2 = v[6], b2 = v[7];   // m=2

    float c0 = (a1 * b2 - a2 * b1) * INV_SQRT2;
    float c1 = (a2 * b0 - a0 * b2) * INV_SQRT2;
    float c2 = (a0 * b1 - a1 * b0) * INV_SQRT2;

    float* o = out + (size_t)a * 9;
    o[0] = a0; o[1] = b0; o[2] = c0;
    o[3] = a1; o[4] = b1; o[5] = c1;
    o[6] = a2; o[7] = b2; o[8] = c2;
}

extern "C" void kernel_launch(void* const* d_in, const int* in_sizes, int n_in,
                              void* d_out, int out_size, void* d_ws, size_t ws_size,
                              hipStream_t stream) {
    const float* vecs      = (const float*)d_in[0];
    const float* W_species = (const float*)d_in[1];
    const float* Emb       = (const float*)d_in[2];
    const float* Wc        = (const float*)d_in[3];
    const int*   centers   = (const int*)d_in[4];
    const int*   neighbors = (const int*)d_in[5];
    const int*   species   = (const int*)d_in[6];

    int E = in_sizes[0] / 3;
    int A = in_sizes[6];

    float* vacc = (float*)d_ws;                 // A*9 floats (accumulator)
    float* G    = vacc + (size_t)A * 9;         // 384 floats

    // Accumulator must be zeroed every call (we accumulate via atomics).
    hipMemsetAsync(vacc, 0, (size_t)A * 9 * sizeof(float), stream);

    build_G_kernel<<<1, 384, 0, stream>>>(W_species, Emb, Wc, G);

    const int threads = 256;
    int eblocks = (E + threads - 1) / threads;
    edge_kernel<<<eblocks, threads, 0, stream>>>(vecs, centers, neighbors,
                                                 species, G, vacc, E);

    int ablocks = (A + threads - 1) / threads;
    finalize_kernel<<<ablocks, threads, 0, stream>>>(vacc, (float*)d_out, A);
}

// Round 2
// 581.745 us; speedup vs baseline: 1.4879x; 1.4879x over previous
//
#include <hip/hip_runtime.h>
#include <math.h>

#define N_RADIAL 8
#define N_PSEUDO 4
#define EMB_DIM 32
#define CUTOFF 5.0f
#define WIDTH 0.5f
#define SQRT3_4PI 0.48860251190291992f   /* sqrt(3/(4*pi)) */
#define INV_SQRT2 0.70710678118654752f
#define PI_F 3.14159265358979323846f

// ---------------------------------------------------------------------------
// G[tc][tn][n][k] = sum_q W_species[tn,q] * Emb[tc, n*4+q] * Wc[n*4+q, k]
// for k = 0,1 ONLY: the reference discards v[:,:,2] (basis uses v0, v1, and
// cross(v0,v1)/sqrt2). 4*4*8*2 = 256 floats.
// ---------------------------------------------------------------------------
__global__ void build_G_kernel(const float* __restrict__ W_species, // (4,4)
                               const float* __restrict__ Emb,       // (4,32)
                               const float* __restrict__ Wc,        // (32,3)
                               float* __restrict__ G) {
    int i = threadIdx.x;            // 256 threads, one per table entry
    int k  = i & 1;
    int n  = (i >> 1) & 7;
    int tn = (i >> 4) & 3;
    int tc = i >> 6;
    float acc = 0.0f;
    #pragma unroll
    for (int q = 0; q < N_PSEUDO; ++q) {
        int d = n * N_PSEUDO + q;
        acc += W_species[tn * N_PSEUDO + q] * Emb[tc * EMB_DIM + d] * Wc[d * 3 + k];
    }
    G[i] = acc;
}

// ---------------------------------------------------------------------------
// Edge kernel: one thread per edge. Rank-1 contribution Y[m] * (s0,s1):
// 6 native f32 atomics into a 32B-aligned row vacc[center][0..5] (stride 8).
// ---------------------------------------------------------------------------
__global__ void edge_kernel(const float* __restrict__ vecs,      // (E,3)
                            const int*   __restrict__ centers,   // (E,)
                            const int*   __restrict__ neighbors, // (E,)
                            const int*   __restrict__ species,   // (A,)
                            const float* __restrict__ G,         // (4,4,8,2)
                            float*       __restrict__ vacc,      // (A,8)
                            int E) {
    __shared__ float Gs[256];
    Gs[threadIdx.x] = G[threadIdx.x];     // blockDim.x == 256
    __syncthreads();

    int e = blockIdx.x * blockDim.x + threadIdx.x;
    if (e >= E) return;

    float vx = vecs[3 * e + 0];
    float vy = vecs[3 * e + 1];
    float vz = vecs[3 * e + 2];

    float r2 = vx * vx + vy * vy + vz * vz;
    float r  = sqrtf(r2);
    if (r >= CUTOFF) return;            // fcut == 0 exactly

    int c  = centers[e];
    int tc = species[c];
    int tn = species[neighbors[e]];

    float rinv = 1.0f / (r + 1e-10f);

    // ShiftedCosine cutoff
    float t = (r - (CUTOFF - WIDTH)) / WIDTH;
    t = fminf(fmaxf(t, 0.0f), 1.0f);
    float fcut = 0.5f * (1.0f + cosf(PI_F * t));

    // R[n] = sin((pi/CUTOFF) * r * (n+1)) via Chebyshev recurrence.
    float theta = (PI_F / CUTOFF) * r;
    float s1, c1;
    sincosf(theta, &s1, &c1);
    float twoc  = 2.0f * c1;
    float sn_m1 = 0.0f;
    float sn    = s1;

    const float* Gp = &Gs[((tc * 4 + tn) * 8) * 2];  // G[tc][tn][*][*], 16 floats
    float s0 = 0.0f, s1a = 0.0f;
    #pragma unroll
    for (int n = 0; n < N_RADIAL; ++n) {
        s0  = fmaf(sn, Gp[n * 2 + 0], s0);
        s1a = fmaf(sn, Gp[n * 2 + 1], s1a);
        float nxt = twoc * sn - sn_m1;
        sn_m1 = sn;
        sn = nxt;
    }
    float coef = rinv * fcut;
    s0 *= coef; s1a *= coef;

    // Y (m = -1,0,1) = (y, z, x)/r * sqrt(3/4pi)
    float Y0 = SQRT3_4PI * vy * rinv;
    float Y1 = SQRT3_4PI * vz * rinv;
    float Y2 = SQRT3_4PI * vx * rinv;

    float* base = vacc + (size_t)c * 8;     // 32B-aligned row, 6 used
    unsafeAtomicAdd(base + 0, Y0 * s0);
    unsafeAtomicAdd(base + 1, Y0 * s1a);
    unsafeAtomicAdd(base + 2, Y1 * s0);
    unsafeAtomicAdd(base + 3, Y1 * s1a);
    unsafeAtomicAdd(base + 4, Y2 * s0);
    unsafeAtomicAdd(base + 5, Y2 * s1a);
}

// ---------------------------------------------------------------------------
// Finalize: out[a][m][k]: k=0 -> v0[m], k=1 -> v1[m], k=2 -> cross(v0,v1)/sqrt2.
// ---------------------------------------------------------------------------
__global__ void finalize_kernel(const float* __restrict__ vacc, // (A,8)
                                float* __restrict__ out,        // (A,3,3)
                                int A) {
    int a = blockIdx.x * blockDim.x + threadIdx.x;
    if (a >= A) return;

    const float* v = vacc + (size_t)a * 8;
    float a0 = v[0], b0 = v[1];   // m=0 (y)
    float a1 = v[2], b1 = v[3];   // m=1 (z)
    float a2 = v[4], b2 = v[5];   // m=2 (x)

    float c0 = (a1 * b2 - a2 * b1) * INV_SQRT2;
    float c1 = (a2 * b0 - a0 * b2) * INV_SQRT2;
    float c2 = (a0 * b1 - a1 * b0) * INV_SQRT2;

    float* o = out + (size_t)a * 9;
    o[0] = a0; o[1] = b0; o[2] = c0;
    o[3] = a1; o[4] = b1; o[5] = c1;
    o[6] = a2; o[7] = b2; o[8] = c2;
}

extern "C" void kernel_launch(void* const* d_in, const int* in_sizes, int n_in,
                              void* d_out, int out_size, void* d_ws, size_t ws_size,
                              hipStream_t stream) {
    const float* vecs      = (const float*)d_in[0];
    const float* W_species = (const float*)d_in[1];
    const float* Emb       = (const float*)d_in[2];
    const float* Wc        = (const float*)d_in[3];
    const int*   centers   = (const int*)d_in[4];
    const int*   neighbors = (const int*)d_in[5];
    const int*   species   = (const int*)d_in[6];

    int E = in_sizes[0] / 3;
    int A = in_sizes[6];

    float* vacc = (float*)d_ws;                 // A*8 floats, 32B rows
    float* G    = vacc + (size_t)A * 8;         // 256 floats

    hipMemsetAsync(vacc, 0, (size_t)A * 8 * sizeof(float), stream);

    build_G_kernel<<<1, 256, 0, stream>>>(W_species, Emb, Wc, G);

    const int threads = 256;
    int eblocks = (E + threads - 1) / threads;
    edge_kernel<<<eblocks, threads, 0, stream>>>(vecs, centers, neighbors,
                                                 species, G, vacc, E);

    int ablocks = (A + threads - 1) / threads;
    finalize_kernel<<<ablocks, threads, 0, stream>>>(vacc, (float*)d_out, A);
}